// Round 6
// baseline (194.791 us; speedup 1.0000x reference)
//
#include <hip/hip_runtime.h>
#include <math.h>

#define BATCH 2
#define SEQ   2048
#define NH    16
#define DH    64
#define DM    1024

typedef __attribute__((ext_vector_type(8))) short bf16x8;
typedef __attribute__((ext_vector_type(8))) unsigned short u16x8;
typedef __attribute__((ext_vector_type(4))) float f32x4;

__device__ __forceinline__ unsigned short f2bf(float f) {
    union { float f; unsigned u; } v; v.f = f;
    unsigned r = v.u + 0x7FFF + ((v.u >> 16) & 1);
    return (unsigned short)(r >> 16);
}
// cheap round-half-up (positive finite inputs; softmax weights)
__device__ __forceinline__ unsigned short f2bf_fast(float f) {
    union { float f; unsigned u; } v; v.f = f;
    return (unsigned short)((v.u + 0x8000u) >> 16);
}

// async global->LDS DMA, 16B per lane; LDS dst = wave-uniform base + lane*16
__device__ __forceinline__ void gl2lds16(const void* g, void* l) {
    __builtin_amdgcn_global_load_lds(
        (const __attribute__((address_space(1))) void*)g,
        (__attribute__((address_space(3))) void*)l,
        16, 0, 0);
}

// 0.125 * log2(e): folded so attn can use raw v_exp_f32 (2^x) directly.
#define QSCALE 0.18033688011112042f

// ---------------------------------------------------------------------------
// conv_fused (round-0): blockIdx < 2048 -> x fp32 -> bf16 ; else weight
// transposes. Standalone x-pass runs at full-chip BW (round-3 lesson: fusing
// it into the occupancy-starved qkv cost +16us).
// ---------------------------------------------------------------------------
__global__ __launch_bounds__(256) void conv_fused(
    const float* __restrict__ x,
    const float* __restrict__ WQ, const float* __restrict__ WK,
    const float* __restrict__ WV, const float* __restrict__ WO,
    unsigned short* __restrict__ xb,
    unsigned short* __restrict__ Wt, unsigned short* __restrict__ WOt)
{
    __shared__ float sT[64][68];
    const int tid = threadIdx.x;

    if (blockIdx.x < 2048) {
        size_t idx = ((size_t)blockIdx.x * 256 + tid) * 8;
        float4 a = *(const float4*)(x + idx);
        float4 b = *(const float4*)(x + idx + 4);
        u16x8 o;
        o[0] = f2bf(a.x); o[1] = f2bf(a.y); o[2] = f2bf(a.z); o[3] = f2bf(a.w);
        o[4] = f2bf(b.x); o[5] = f2bf(b.y); o[6] = f2bf(b.z); o[7] = f2bf(b.w);
        *(u16x8*)(xb + idx) = o;
        return;
    }
    const int t = blockIdx.x - 2048;
    if (t < 768) {
        int m = t >> 8, rem = t & 255, h = rem >> 4, dblk = rem & 15;
        const float* W = (m == 0) ? WQ : (m == 1) ? WK : WV;
        const float* in = W + (size_t)h * 65536 + dblk * 4096;
#pragma unroll
        for (int it = 0; it < 4; it++) {
            int idx = it * 1024 + tid * 4;
            int r = idx >> 6, c = idx & 63;
            *(float4*)(&sT[r][c]) = *(const float4*)(&in[(size_t)r * 64 + c]);
        }
        __syncthreads();
        unsigned short* out = Wt + (size_t)m * 1048576 + (size_t)h * 65536 + dblk * 64;
#pragma unroll
        for (int it = 0; it < 4; it++) {
            int idx = it * 1024 + tid * 4;
            int e = idx >> 6, d0 = idx & 63;
            ushort4 o;
            unsigned short* op = (unsigned short*)&o;
#pragma unroll
            for (int j = 0; j < 4; j++) op[j] = f2bf(sT[d0 + j][e]);
            *(ushort4*)&out[(size_t)e * 1024 + d0] = o;
        }
    } else {
        int tt = t - 768, rblk = tt >> 4, cblk = tt & 15;
        const float* in = WO + (size_t)rblk * 64 * 1024 + cblk * 64;
#pragma unroll
        for (int it = 0; it < 4; it++) {
            int idx = it * 1024 + tid * 4;
            int r = idx >> 6, c = idx & 63;
            *(float4*)(&sT[r][c]) = *(const float4*)(&in[(size_t)r * 1024 + c]);
        }
        __syncthreads();
        unsigned short* out = WOt + (size_t)cblk * 64 * 1024 + rblk * 64;
#pragma unroll
        for (int it = 0; it < 4; it++) {
            int idx = it * 1024 + tid * 4;
            int d = idx >> 6, he0 = idx & 63;
            ushort4 o;
            unsigned short* op = (unsigned short*)&o;
#pragma unroll
            for (int j = 0; j < 4; j++) op[j] = f2bf(sT[he0 + j][d]);
            *(ushort4*)&out[(size_t)d * 1024 + he0] = o;
        }
    }
}

// ---------------------------------------------------------------------------
// qkv_mfma v4 (round-0 structure, best measured 43.9us): async-prefetch LDS
// double-buffer, ONE barrier/iter. 2 blocks/CU (reg-limited 124+64 AGPR;
// round-1 lesson: forcing 3 waves/SIMD spills catastrophically).
// Q output scale folds log2(e) for attn's exp2 path.
// ---------------------------------------------------------------------------
__global__ __launch_bounds__(256) void qkv_mfma(
    const unsigned short* __restrict__ xb,
    const unsigned short* __restrict__ Wt,
    const float* __restrict__ bQ, const float* __restrict__ bK,
    const float* __restrict__ bV,
    unsigned short* __restrict__ Q, unsigned short* __restrict__ K,
    unsigned short* __restrict__ Vt)
{
    __shared__ __align__(16) unsigned short sA[2][128 * 64];
    __shared__ __align__(16) unsigned short sB[2][128 * 64];

    const int rowTile = blockIdx.x;
    const int m  = blockIdx.y >> 3;
    const int hp = blockIdx.y & 7;
    const unsigned short* Wm = Wt + (size_t)m * 1048576 + (size_t)hp * 2 * 65536;

    const int tid  = threadIdx.x;
    const int w    = tid >> 6;
    const int lane = tid & 63;
    const int l15  = lane & 15;
    const int quad = lane >> 4;
    const int rw   = (w & 1) * 64;
    const int cw   = (w >> 1) * 64;
    const int rowBase = rowTile * 128;

    const int crow = lane >> 3;
    const int ccs  = (((lane & 7) ^ crow) * 8);

    f32x4 acc[4][4];
#pragma unroll
    for (int i = 0; i < 4; i++)
#pragma unroll
        for (int j = 0; j < 4; j++) acc[i][j] = (f32x4){0.f, 0.f, 0.f, 0.f};

    // prologue: stage tile 0 into buffer 0
#pragma unroll
    for (int c = 0; c < 4; c++) {
        const int chunk = w * 4 + c;
        const int rr = chunk * 8 + crow;
        gl2lds16(&xb[(size_t)(rowBase + rr) * DM + ccs], &sA[0][chunk * 512]);
        gl2lds16(&Wm[(size_t)rr * DM + ccs],             &sB[0][chunk * 512]);
    }

    for (int kt = 0; kt < 16; kt++) {
        __syncthreads();   // DMA(kt) landed; buf(kt+1&1) free for overwrite
        if (kt < 15) {
            const int k1 = (kt + 1) * 64;
            unsigned short* dA = sA[(kt + 1) & 1];
            unsigned short* dB = sB[(kt + 1) & 1];
#pragma unroll
            for (int c = 0; c < 4; c++) {
                const int chunk = w * 4 + c;
                const int rr = chunk * 8 + crow;
                gl2lds16(&xb[(size_t)(rowBase + rr) * DM + k1 + ccs], &dA[chunk * 512]);
                gl2lds16(&Wm[(size_t)rr * DM + k1 + ccs],             &dB[chunk * 512]);
            }
        }
        const unsigned short* pA = sA[kt & 1];
        const unsigned short* pB = sB[kt & 1];

#pragma unroll
        for (int ks = 0; ks < 2; ks++) {
            bf16x8 af[4], bf[4];
#pragma unroll
            for (int i = 0; i < 4; i++) {
                int ar = rw + i * 16 + l15;
                af[i] = *(const bf16x8*)&pA[ar * 64 + (((ks * 4 + quad) ^ (ar & 7)) * 8)];
            }
#pragma unroll
            for (int j = 0; j < 4; j++) {
                int br = cw + j * 16 + l15;
                bf[j] = *(const bf16x8*)&pB[br * 64 + (((ks * 4 + quad) ^ (br & 7)) * 8)];
            }
            if (m == 2) {
#pragma unroll
                for (int i = 0; i < 4; i++)
#pragma unroll
                    for (int j = 0; j < 4; j++)
                        acc[i][j] = __builtin_amdgcn_mfma_f32_16x16x32_bf16(
                            af[i], bf[j], acc[i][j], 0, 0, 0);
            } else {
#pragma unroll
                for (int i = 0; i < 4; i++)
#pragma unroll
                    for (int j = 0; j < 4; j++)
                        acc[i][j] = __builtin_amdgcn_mfma_f32_16x16x32_bf16(
                            bf[j], af[i], acc[i][j], 0, 0, 0);
            }
        }
    }

    if (m == 2) {
        // D[m=s][n=e]: lane holds fixed e, 4 consecutive s -> Vt[e][s] packed
#pragma unroll
        for (int j = 0; j < 4; j++) {
            int col = cw + j * 16 + l15;
            int h = hp * 2 + (col >> 6);
            int e = col & 63;
            float bv = bV[h * DH + e];
#pragma unroll
            for (int i = 0; i < 4; i++) {
                int row0 = rowBase + rw + i * 16 + quad * 4;
                int b = row0 >> 11, s0 = row0 & 2047;
                ushort4 o;
                unsigned short* op = (unsigned short*)&o;
#pragma unroll
                for (int r = 0; r < 4; r++) op[r] = f2bf(acc[i][j][r] + bv);
                *(ushort4*)&Vt[(((size_t)b * NH + h) * DH + e) * SEQ + s0] = o;
            }
        }
    } else {
        // D[m=e][n=s]: lane holds fixed s, 4 consecutive e -> [s][e] packed
        const float* bias = (m == 0) ? bQ : bK;
        unsigned short* Out = (m == 0) ? Q : K;
        const float scale = (m == 0) ? QSCALE : 1.0f;
        float4 bb[4];
        int hj[4], e0j[4];
#pragma unroll
        for (int j = 0; j < 4; j++) {
            int col0 = cw + j * 16 + quad * 4;
            hj[j] = hp * 2 + (col0 >> 6);
            e0j[j] = col0 & 63;
            bb[j] = *(const float4*)&bias[hj[j] * DH + e0j[j]];
        }
#pragma unroll
        for (int i = 0; i < 4; i++) {
            int row = rowBase + rw + i * 16 + l15;
            int b = row >> 11, s = row & 2047;
#pragma unroll
            for (int j = 0; j < 4; j++) {
                const float* bp = (const float*)&bb[j];
                ushort4 o;
                unsigned short* op = (unsigned short*)&o;
#pragma unroll
                for (int r = 0; r < 4; r++)
                    op[r] = f2bf((acc[i][j][r] + bp[r]) * scale);
                *(ushort4*)&Out[(((size_t)b * NH + hj[j]) * SEQ + s) * DH + e0j[j]] = o;
            }
        }
    }
}

// ---------------------------------------------------------------------------
// attn_mfma v10: v9 + CU-load-balanced qt remap.
// Round-5 counters: LDS fits 4 blocks/CU but OccupancyPercent averaged 24%
// because descending-qt dispatch gives CU c the qt set {31-k,23-k,15-k,7-k}
// (k=c>>5): 80 iters on CUs 0-31 vs 52 on CUs 224-255; duration is bound by
// the 80-iter CUs while drained CUs idle (tail). Remap pairs long+short:
//   t = bid>>5 ; qt = (t&1) ? t>>1 : 31-(t>>1)   (31,0,30,1,29,2,...)
// -> every aligned 4-t-group window (= one block per CU per round) holds two
// pairs each summing 33 iters -> all CUs get 66 iters. Bijective; per-block
// work, traffic, numerics unchanged.
// ---------------------------------------------------------------------------
__global__ __launch_bounds__(256) void attn_mfma(
    const unsigned short* __restrict__ Q,    // [B][H][S][E] bf16, pre-scaled
    const unsigned short* __restrict__ K,    // [B][H][S][E] bf16
    const unsigned short* __restrict__ Vt,   // [B][H][E][S] bf16
    unsigned short* __restrict__ Z)          // [B][S][H*E] bf16
{
    __shared__ __align__(16) unsigned short sK[2][64 * 64];
    __shared__ __align__(16) unsigned short sV[2][64 * 64];
    __shared__ __align__(16) unsigned short sP[64 * 64];

    const int h  = blockIdx.x & 15;
    const int b  = (blockIdx.x >> 4) & 1;
    const int t  = blockIdx.x >> 5;           // 0..31
    const int qt = (t & 1) ? (t >> 1) : (31 - (t >> 1));  // balanced interleave

    const int tid  = threadIdx.x;
    const int w    = tid >> 6;
    const int lane = tid & 63;
    const int l15  = lane & 15;
    const int quad = lane >> 4;
    const int row  = w * 16 + l15;            // q-row within the 64-row tile

    const size_t headOff = ((size_t)b * NH + h) * SEQ * DH;
    const unsigned short* Qh  = Q  + headOff;
    const unsigned short* Kh  = K  + headOff;
    const unsigned short* Vth = Vt + headOff;   // [E][S]

    const unsigned short* qrow =
        Qh + (size_t)(qt * 64 + row) * DH + quad * 8;
    bf16x8 q0 = *(const bf16x8*)(qrow);
    bf16x8 q1 = *(const bf16x8*)(qrow + 32);

    f32x4 O[4];
#pragma unroll
    for (int s = 0; s < 4; s++) O[s] = (f32x4){0.f, 0.f, 0.f, 0.f};
    float la = 0.f;

    const int crow = lane >> 3;
    const int ccs  = (((lane & 7) ^ crow) * 8);

    // prologue: stage tile 0 into buffer 0
#pragma unroll
    for (int c = 0; c < 2; c++) {
        const int chunk = w * 2 + c;
        const int rr = chunk * 8 + crow;
        gl2lds16(&Kh[(size_t)rr * DH + ccs],   &sK[0][chunk * 512]);
        gl2lds16(&Vth[(size_t)rr * SEQ + ccs], &sV[0][chunk * 512]);
    }

    // P LDS addressing: element (row, col) lives at
    //   row*64 + ((col>>3) ^ (row&7))*8 + (col&7)
    const int pwBase = row * 64 + (quad & 1) * 4;   // + chunk-swizzle per sub
    const int prBase = row * 64;

    for (int kt = 0; kt <= qt; kt++) {
        __syncthreads();   // DMA(kt) landed; other buffer free
        if (kt < qt) {
            const int k1 = (kt + 1) * 64;
            unsigned short* dK = sK[(kt + 1) & 1];
            unsigned short* dV = sV[(kt + 1) & 1];
#pragma unroll
            for (int c = 0; c < 2; c++) {
                const int chunk = w * 2 + c;
                const int rr = chunk * 8 + crow;
                gl2lds16(&Kh[(size_t)(k1 + rr) * DH + ccs], &dK[chunk * 512]);
                gl2lds16(&Vth[(size_t)rr * SEQ + k1 + ccs], &dV[chunk * 512]);
            }
        }
        const unsigned short* pK = sK[kt & 1];
        const unsigned short* pV = sV[kt & 1];

        bf16x8 kf[8], vf[8];
#pragma unroll
        for (int ks = 0; ks < 2; ks++)
#pragma unroll
            for (int sub = 0; sub < 4; sub++) {
                int rr = sub * 16 + l15;
                int sw = ((ks * 4 + quad) ^ (rr & 7)) * 8;
                kf[ks * 4 + sub] = *(const bf16x8*)&pK[rr * 64 + sw];
                vf[ks * 4 + sub] = *(const bf16x8*)&pV[rr * 64 + sw];
            }

        // ---- S^T = K Q^T (lane holds col=row-of-Q fixed, 16 k-rows)
        f32x4 S4[4];
#pragma unroll
        for (int s = 0; s < 4; s++) S4[s] = (f32x4){0.f, 0.f, 0.f, 0.f};
#pragma unroll
        for (int sub = 0; sub < 4; sub++)
            S4[sub] = __builtin_amdgcn_mfma_f32_16x16x32_bf16(
                kf[sub], q0, S4[sub], 0, 0, 0);
#pragma unroll
        for (int sub = 0; sub < 4; sub++)
            S4[sub] = __builtin_amdgcn_mfma_f32_16x16x32_bf16(
                kf[4 + sub], q1, S4[sub], 0, 0, 0);

        // ---- softmax numerators (Q pre-scaled by log2e/8 -> bare exp2)
        const bool diag = (kt == qt);
#pragma unroll
        for (int sub = 0; sub < 4; sub++) {
            ushort4 o;
            unsigned short* op = (unsigned short*)&o;
#pragma unroll
            for (int r = 0; r < 4; r++) {
                float p = __builtin_exp2f(S4[sub][r]);
                if (diag && (sub * 16 + quad * 4 + r > row)) p = 0.f;
                la += p;
                op[r] = f2bf_fast(p);
            }
            int chunk = sub * 2 + (quad >> 1);
            *(ushort4*)&sP[pwBase + ((chunk ^ (row & 7)) * 8)] = o;
        }
        __builtin_amdgcn_wave_barrier();   // sP rows are wave-private

        // ---- O += V^T P^T
#pragma unroll
        for (int ks = 0; ks < 2; ks++) {
            bf16x8 pb = *(const bf16x8*)
                &sP[prBase + (((ks * 4 + quad) ^ (row & 7)) * 8)];
#pragma unroll
            for (int sub = 0; sub < 4; sub++)
                O[sub] = __builtin_amdgcn_mfma_f32_16x16x32_bf16(
                    vf[ks * 4 + sub], pb, O[sub], 0, 0, 0);
        }
        __builtin_amdgcn_wave_barrier();
    }

    // ---- denominator: sum partials across the 4 quads (same l15)
    la += __shfl_xor(la, 16, 64);
    la += __shfl_xor(la, 32, 64);
    const float rl = 1.0f / la;

    // ---- store: lane owns q = qt*64 + row, e = sub*16 + quad*4 + r
    {
        const int q = qt * 64 + row;
        unsigned short* zrow = Z + ((size_t)b * SEQ + q) * DM + h * DH;
#pragma unroll
        for (int sub = 0; sub < 4; sub++) {
            ushort4 o;
            unsigned short* op = (unsigned short*)&o;
#pragma unroll
            for (int r = 0; r < 4; r++) op[r] = f2bf(O[sub][r] * rl);
            *(ushort4*)&zrow[sub * 16 + quad * 4] = o;
        }
    }
}

// ---------------------------------------------------------------------------
// out_mfma v4: async-prefetch LDS double-buffer, one barrier/iter.
// ---------------------------------------------------------------------------
__global__ __launch_bounds__(256) void out_mfma(
    const unsigned short* __restrict__ Zb,
    const unsigned short* __restrict__ WOt,
    const float* __restrict__ bO,
    float* __restrict__ out)
{
    __shared__ __align__(16) unsigned short sA[2][64 * 64];
    __shared__ __align__(16) unsigned short sB[2][128 * 64];

    const int rowTile = blockIdx.x;
    const int colTile = blockIdx.y;
    const int rowBase = rowTile * 64;
    const int colBase = colTile * 128;

    const int tid  = threadIdx.x;
    const int w    = tid >> 6;
    const int lane = tid & 63;
    const int l15  = lane & 15;
    const int quad = lane >> 4;
    const int rw   = (w & 1) * 32;
    const int cw   = (w >> 1) * 64;

    const int crow = lane >> 3;
    const int ccs  = (((lane & 7) ^ crow) * 8);

    f32x4 acc[2][4];
#pragma unroll
    for (int i = 0; i < 2; i++)
#pragma unroll
        for (int j = 0; j < 4; j++) acc[i][j] = (f32x4){0.f, 0.f, 0.f, 0.f};

    // prologue: stage tile 0
#pragma unroll
    for (int c = 0; c < 2; c++) {
        const int chunk = w * 2 + c;
        const int rr = chunk * 8 + crow;
        gl2lds16(&Zb[(size_t)(rowBase + rr) * DM + ccs], &sA[0][chunk * 512]);
    }
#pragma unroll
    for (int c = 0; c < 4; c++) {
        const int chunk = w * 4 + c;
        const int rr = chunk * 8 + crow;
        gl2lds16(&WOt[(size_t)(colBase + rr) * DM + ccs], &sB[0][chunk * 512]);
    }

    for (int kt = 0; kt < 16; kt++) {
        __syncthreads();
        if (kt < 15) {
            const int k1 = (kt + 1) * 64;
            unsigned short* dA = sA[(kt + 1) & 1];
            unsigned short* dB = sB[(kt + 1) & 1];
#pragma unroll
            for (int c = 0; c < 2; c++) {
                const int chunk = w * 2 + c;
                const int rr = chunk * 8 + crow;
                gl2lds16(&Zb[(size_t)(rowBase + rr) * DM + k1 + ccs], &dA[chunk * 512]);
            }
#pragma unroll
            for (int c = 0; c < 4; c++) {
                const int chunk = w * 4 + c;
                const int rr = chunk * 8 + crow;
                gl2lds16(&WOt[(size_t)(colBase + rr) * DM + k1 + ccs], &dB[chunk * 512]);
            }
        }
        const unsigned short* pA = sA[kt & 1];
        const unsigned short* pB = sB[kt & 1];

#pragma unroll
        for (int ks = 0; ks < 2; ks++) {
            bf16x8 af[2], bf[4];
#pragma unroll
            for (int i = 0; i < 2; i++) {
                int ar = rw + i * 16 + l15;
                af[i] = *(const bf16x8*)&pA[ar * 64 + (((ks * 4 + quad) ^ (ar & 7)) * 8)];
            }
#pragma unroll
            for (int j = 0; j < 4; j++) {
                int br = cw + j * 16 + l15;
                bf[j] = *(const bf16x8*)&pB[br * 64 + (((ks * 4 + quad) ^ (br & 7)) * 8)];
            }
#pragma unroll
            for (int i = 0; i < 2; i++)
#pragma unroll
                for (int j = 0; j < 4; j++)
                    acc[i][j] = __builtin_amdgcn_mfma_f32_16x16x32_bf16(
                        bf[j], af[i], acc[i][j], 0, 0, 0);
        }
    }

#pragma unroll
    for (int i = 0; i < 2; i++) {
        int row = rowBase + rw + i * 16 + l15;
#pragma unroll
        for (int j = 0; j < 4; j++) {
            int col0 = colBase + cw + j * 16 + quad * 4;
            float4 o;
            o.x = acc[i][j][0] + bO[col0 + 0];
            o.y = acc[i][j][1] + bO[col0 + 1];
            o.z = acc[i][j][2] + bO[col0 + 2];
            o.w = acc[i][j][3] + bO[col0 + 3];
            *(float4*)&out[(size_t)row * DM + col0] = o;
        }
    }
}

// ---------------------------------------------------------------------------
extern "C" void kernel_launch(void* const* d_in, const int* in_sizes, int n_in,
                              void* d_out, int out_size, void* d_ws, size_t ws_size,
                              hipStream_t stream)
{
    const float* x  = (const float*)d_in[0];
    const float* WQ = (const float*)d_in[1];
    const float* WK = (const float*)d_in[2];
    const float* WV = (const float*)d_in[3];
    const float* WO = (const float*)d_in[4];
    const float* bQ = (const float*)d_in[5];
    const float* bK = (const float*)d_in[6];
    const float* bV = (const float*)d_in[7];
    const float* bO = (const float*)d_in[8];
    float* out = (float*)d_out;

    const size_t M4 = 4194304;
    unsigned short* xb  = (unsigned short*)d_ws;       // 4M (reused as Zb)
    unsigned short* Wt  = xb + M4;                     // 3M
    unsigned short* WOt = Wt + 3 * 1048576;            // 1M
    unsigned short* Qw  = WOt + 1048576;               // 4M
    unsigned short* Kw  = Qw + M4;                     // 4M
    unsigned short* Vtw = Kw + M4;                     // 4M (transposed V)
    unsigned short* Zb  = xb;

    conv_fused<<<3072, 256, 0, stream>>>(x, WQ, WK, WV, WO, xb, Wt, WOt);

    dim3 g1(32, 24);
    qkv_mfma<<<g1, 256, 0, stream>>>(xb, Wt, bQ, bK, bV, Qw, Kw, Vtw);

    attn_mfma<<<1024, 256, 0, stream>>>(Qw, Kw, Vtw, Zb);

    dim3 g3(64, 8);
    out_mfma<<<g3, 256, 0, stream>>>(Zb, WOt, bO, out);
}

// Round 7
// 192.785 us; speedup vs baseline: 1.0104x; 1.0104x over previous
//
#include <hip/hip_runtime.h>
#include <math.h>

#define BATCH 2
#define SEQ   2048
#define NH    16
#define DH    64
#define DM    1024

typedef __attribute__((ext_vector_type(8))) short bf16x8;
typedef __attribute__((ext_vector_type(8))) unsigned short u16x8;
typedef __attribute__((ext_vector_type(4))) float f32x4;

__device__ __forceinline__ unsigned short f2bf(float f) {
    union { float f; unsigned u; } v; v.f = f;
    unsigned r = v.u + 0x7FFF + ((v.u >> 16) & 1);
    return (unsigned short)(r >> 16);
}
// cheap round-half-up (positive finite inputs; softmax weights)
__device__ __forceinline__ unsigned short f2bf_fast(float f) {
    union { float f; unsigned u; } v; v.f = f;
    return (unsigned short)((v.u + 0x8000u) >> 16);
}

// async global->LDS DMA, 16B per lane; LDS dst = wave-uniform base + lane*16
__device__ __forceinline__ void gl2lds16(const void* g, void* l) {
    __builtin_amdgcn_global_load_lds(
        (const __attribute__((address_space(1))) void*)g,
        (__attribute__((address_space(3))) void*)l,
        16, 0, 0);
}

// 0.125 * log2(e): folded so attn can use raw v_exp_f32 (2^x) directly.
#define QSCALE 0.18033688011112042f

// ---------------------------------------------------------------------------
// conv_fused (round-0): blockIdx < 2048 -> x fp32 -> bf16 ; else weight
// transposes. Standalone x-pass runs at full-chip BW (round-3 lesson: fusing
// it into the occupancy-starved qkv cost +16us).
// ---------------------------------------------------------------------------
__global__ __launch_bounds__(256) void conv_fused(
    const float* __restrict__ x,
    const float* __restrict__ WQ, const float* __restrict__ WK,
    const float* __restrict__ WV, const float* __restrict__ WO,
    unsigned short* __restrict__ xb,
    unsigned short* __restrict__ Wt, unsigned short* __restrict__ WOt)
{
    __shared__ float sT[64][68];
    const int tid = threadIdx.x;

    if (blockIdx.x < 2048) {
        size_t idx = ((size_t)blockIdx.x * 256 + tid) * 8;
        float4 a = *(const float4*)(x + idx);
        float4 b = *(const float4*)(x + idx + 4);
        u16x8 o;
        o[0] = f2bf(a.x); o[1] = f2bf(a.y); o[2] = f2bf(a.z); o[3] = f2bf(a.w);
        o[4] = f2bf(b.x); o[5] = f2bf(b.y); o[6] = f2bf(b.z); o[7] = f2bf(b.w);
        *(u16x8*)(xb + idx) = o;
        return;
    }
    const int t = blockIdx.x - 2048;
    if (t < 768) {
        int m = t >> 8, rem = t & 255, h = rem >> 4, dblk = rem & 15;
        const float* W = (m == 0) ? WQ : (m == 1) ? WK : WV;
        const float* in = W + (size_t)h * 65536 + dblk * 4096;
#pragma unroll
        for (int it = 0; it < 4; it++) {
            int idx = it * 1024 + tid * 4;
            int r = idx >> 6, c = idx & 63;
            *(float4*)(&sT[r][c]) = *(const float4*)(&in[(size_t)r * 64 + c]);
        }
        __syncthreads();
        unsigned short* out = Wt + (size_t)m * 1048576 + (size_t)h * 65536 + dblk * 64;
#pragma unroll
        for (int it = 0; it < 4; it++) {
            int idx = it * 1024 + tid * 4;
            int e = idx >> 6, d0 = idx & 63;
            ushort4 o;
            unsigned short* op = (unsigned short*)&o;
#pragma unroll
            for (int j = 0; j < 4; j++) op[j] = f2bf(sT[d0 + j][e]);
            *(ushort4*)&out[(size_t)e * 1024 + d0] = o;
        }
    } else {
        int tt = t - 768, rblk = tt >> 4, cblk = tt & 15;
        const float* in = WO + (size_t)rblk * 64 * 1024 + cblk * 64;
#pragma unroll
        for (int it = 0; it < 4; it++) {
            int idx = it * 1024 + tid * 4;
            int r = idx >> 6, c = idx & 63;
            *(float4*)(&sT[r][c]) = *(const float4*)(&in[(size_t)r * 1024 + c]);
        }
        __syncthreads();
        unsigned short* out = WOt + (size_t)cblk * 64 * 1024 + rblk * 64;
#pragma unroll
        for (int it = 0; it < 4; it++) {
            int idx = it * 1024 + tid * 4;
            int d = idx >> 6, he0 = idx & 63;
            ushort4 o;
            unsigned short* op = (unsigned short*)&o;
#pragma unroll
            for (int j = 0; j < 4; j++) op[j] = f2bf(sT[he0 + j][d]);
            *(ushort4*)&out[(size_t)d * 1024 + he0] = o;
        }
    }
}

// ---------------------------------------------------------------------------
// qkv_mfma v4 (round-0 structure, best measured 43.9us): async-prefetch LDS
// double-buffer, ONE barrier/iter. 2 blocks/CU (reg-limited 124+64 AGPR;
// round-1 lesson: forcing 3 waves/SIMD spills catastrophically).
// Q output scale folds log2(e) for attn's exp2 path.
// ---------------------------------------------------------------------------
__global__ __launch_bounds__(256) void qkv_mfma(
    const unsigned short* __restrict__ xb,
    const unsigned short* __restrict__ Wt,
    const float* __restrict__ bQ, const float* __restrict__ bK,
    const float* __restrict__ bV,
    unsigned short* __restrict__ Q, unsigned short* __restrict__ K,
    unsigned short* __restrict__ Vt)
{
    __shared__ __align__(16) unsigned short sA[2][128 * 64];
    __shared__ __align__(16) unsigned short sB[2][128 * 64];

    const int rowTile = blockIdx.x;
    const int m  = blockIdx.y >> 3;
    const int hp = blockIdx.y & 7;
    const unsigned short* Wm = Wt + (size_t)m * 1048576 + (size_t)hp * 2 * 65536;

    const int tid  = threadIdx.x;
    const int w    = tid >> 6;
    const int lane = tid & 63;
    const int l15  = lane & 15;
    const int quad = lane >> 4;
    const int rw   = (w & 1) * 64;
    const int cw   = (w >> 1) * 64;
    const int rowBase = rowTile * 128;

    const int crow = lane >> 3;
    const int ccs  = (((lane & 7) ^ crow) * 8);

    f32x4 acc[4][4];
#pragma unroll
    for (int i = 0; i < 4; i++)
#pragma unroll
        for (int j = 0; j < 4; j++) acc[i][j] = (f32x4){0.f, 0.f, 0.f, 0.f};

    // prologue: stage tile 0 into buffer 0
#pragma unroll
    for (int c = 0; c < 4; c++) {
        const int chunk = w * 4 + c;
        const int rr = chunk * 8 + crow;
        gl2lds16(&xb[(size_t)(rowBase + rr) * DM + ccs], &sA[0][chunk * 512]);
        gl2lds16(&Wm[(size_t)rr * DM + ccs],             &sB[0][chunk * 512]);
    }

    for (int kt = 0; kt < 16; kt++) {
        __syncthreads();   // DMA(kt) landed; buf(kt+1&1) free for overwrite
        if (kt < 15) {
            const int k1 = (kt + 1) * 64;
            unsigned short* dA = sA[(kt + 1) & 1];
            unsigned short* dB = sB[(kt + 1) & 1];
#pragma unroll
            for (int c = 0; c < 4; c++) {
                const int chunk = w * 4 + c;
                const int rr = chunk * 8 + crow;
                gl2lds16(&xb[(size_t)(rowBase + rr) * DM + k1 + ccs], &dA[chunk * 512]);
                gl2lds16(&Wm[(size_t)rr * DM + k1 + ccs],             &dB[chunk * 512]);
            }
        }
        const unsigned short* pA = sA[kt & 1];
        const unsigned short* pB = sB[kt & 1];

#pragma unroll
        for (int ks = 0; ks < 2; ks++) {
            bf16x8 af[4], bf[4];
#pragma unroll
            for (int i = 0; i < 4; i++) {
                int ar = rw + i * 16 + l15;
                af[i] = *(const bf16x8*)&pA[ar * 64 + (((ks * 4 + quad) ^ (ar & 7)) * 8)];
            }
#pragma unroll
            for (int j = 0; j < 4; j++) {
                int br = cw + j * 16 + l15;
                bf[j] = *(const bf16x8*)&pB[br * 64 + (((ks * 4 + quad) ^ (br & 7)) * 8)];
            }
            if (m == 2) {
#pragma unroll
                for (int i = 0; i < 4; i++)
#pragma unroll
                    for (int j = 0; j < 4; j++)
                        acc[i][j] = __builtin_amdgcn_mfma_f32_16x16x32_bf16(
                            af[i], bf[j], acc[i][j], 0, 0, 0);
            } else {
#pragma unroll
                for (int i = 0; i < 4; i++)
#pragma unroll
                    for (int j = 0; j < 4; j++)
                        acc[i][j] = __builtin_amdgcn_mfma_f32_16x16x32_bf16(
                            bf[j], af[i], acc[i][j], 0, 0, 0);
            }
        }
    }

    if (m == 2) {
        // D[m=s][n=e]: lane holds fixed e, 4 consecutive s -> Vt[e][s] packed
#pragma unroll
        for (int j = 0; j < 4; j++) {
            int col = cw + j * 16 + l15;
            int h = hp * 2 + (col >> 6);
            int e = col & 63;
            float bv = bV[h * DH + e];
#pragma unroll
            for (int i = 0; i < 4; i++) {
                int row0 = rowBase + rw + i * 16 + quad * 4;
                int b = row0 >> 11, s0 = row0 & 2047;
                ushort4 o;
                unsigned short* op = (unsigned short*)&o;
#pragma unroll
                for (int r = 0; r < 4; r++) op[r] = f2bf(acc[i][j][r] + bv);
                *(ushort4*)&Vt[(((size_t)b * NH + h) * DH + e) * SEQ + s0] = o;
            }
        }
    } else {
        // D[m=e][n=s]: lane holds fixed s, 4 consecutive e -> [s][e] packed
        const float* bias = (m == 0) ? bQ : bK;
        unsigned short* Out = (m == 0) ? Q : K;
        const float scale = (m == 0) ? QSCALE : 1.0f;
        float4 bb[4];
        int hj[4], e0j[4];
#pragma unroll
        for (int j = 0; j < 4; j++) {
            int col0 = cw + j * 16 + quad * 4;
            hj[j] = hp * 2 + (col0 >> 6);
            e0j[j] = col0 & 63;
            bb[j] = *(const float4*)&bias[hj[j] * DH + e0j[j]];
        }
#pragma unroll
        for (int i = 0; i < 4; i++) {
            int row = rowBase + rw + i * 16 + l15;
            int b = row >> 11, s = row & 2047;
#pragma unroll
            for (int j = 0; j < 4; j++) {
                const float* bp = (const float*)&bb[j];
                ushort4 o;
                unsigned short* op = (unsigned short*)&o;
#pragma unroll
                for (int r = 0; r < 4; r++)
                    op[r] = f2bf((acc[i][j][r] + bp[r]) * scale);
                *(ushort4*)&Out[(((size_t)b * NH + hj[j]) * SEQ + s) * DH + e0j[j]] = o;
            }
        }
    }
}

// ---------------------------------------------------------------------------
// attn_mfma v11: v10 structure + STRIDE-8 CU-balanced qt remap.
// Dispatch model (now pinned by two independent measurements):
//   block bid -> XCD (bid&7), local slot bid>>3; with 1024 blocks and 4
//   blocks/CU, CU c hosts bids {c, c+256, c+512, c+768}, i.e. t-groups
//   t = {k, k+8, k+16, k+24}, k = (c>>5) & 7.
//   v9  (qt=31-t):          per-CU iters 80..52 (imbalanced, dur 44.2us)
//   v10 (pair-within-4-t):  per-CU iters 104..28 (worse, dur 50.5us) --
//       regression PREDICTED by this model, falsifying the consecutive-t one.
// Balanced remap over the stride-8 classes (k=t&7, j=t>>3):
//   qt = j==0 ? 31-k : j==1 ? 16+k : j==2 ? 15-k : k
// Per-k sum = (31-k)+(16+k)+(15-k)+k = 62 for ALL k -> every CU 66 iters.
// Bijective (j-rows cover 24-31,16-23,8-15,0-7). Work/traffic unchanged.
// ---------------------------------------------------------------------------
__global__ __launch_bounds__(256) void attn_mfma(
    const unsigned short* __restrict__ Q,    // [B][H][S][E] bf16, pre-scaled
    const unsigned short* __restrict__ K,    // [B][H][S][E] bf16
    const unsigned short* __restrict__ Vt,   // [B][H][E][S] bf16
    unsigned short* __restrict__ Z)          // [B][S][H*E] bf16
{
    __shared__ __align__(16) unsigned short sK[2][64 * 64];
    __shared__ __align__(16) unsigned short sV[2][64 * 64];
    __shared__ __align__(16) unsigned short sP[64 * 64];

    const int h  = blockIdx.x & 15;
    const int b  = (blockIdx.x >> 4) & 1;
    const int t  = blockIdx.x >> 5;           // 0..31
    const int kk = t & 7, jj = t >> 3;
    const int qt = (jj == 0) ? (31 - kk)
                 : (jj == 1) ? (16 + kk)
                 : (jj == 2) ? (15 - kk) : kk;

    const int tid  = threadIdx.x;
    const int w    = tid >> 6;
    const int lane = tid & 63;
    const int l15  = lane & 15;
    const int quad = lane >> 4;
    const int row  = w * 16 + l15;            // q-row within the 64-row tile

    const size_t headOff = ((size_t)b * NH + h) * SEQ * DH;
    const unsigned short* Qh  = Q  + headOff;
    const unsigned short* Kh  = K  + headOff;
    const unsigned short* Vth = Vt + headOff;   // [E][S]

    const unsigned short* qrow =
        Qh + (size_t)(qt * 64 + row) * DH + quad * 8;
    bf16x8 q0 = *(const bf16x8*)(qrow);
    bf16x8 q1 = *(const bf16x8*)(qrow + 32);

    f32x4 O[4];
#pragma unroll
    for (int s = 0; s < 4; s++) O[s] = (f32x4){0.f, 0.f, 0.f, 0.f};
    float la = 0.f;

    const int crow = lane >> 3;
    const int ccs  = (((lane & 7) ^ crow) * 8);

    // prologue: stage tile 0 into buffer 0
#pragma unroll
    for (int c = 0; c < 2; c++) {
        const int chunk = w * 2 + c;
        const int rr = chunk * 8 + crow;
        gl2lds16(&Kh[(size_t)rr * DH + ccs],   &sK[0][chunk * 512]);
        gl2lds16(&Vth[(size_t)rr * SEQ + ccs], &sV[0][chunk * 512]);
    }

    // P LDS addressing: element (row, col) lives at
    //   row*64 + ((col>>3) ^ (row&7))*8 + (col&7)
    const int pwBase = row * 64 + (quad & 1) * 4;   // + chunk-swizzle per sub
    const int prBase = row * 64;

    for (int kt = 0; kt <= qt; kt++) {
        __syncthreads();   // DMA(kt) landed; other buffer free
        if (kt < qt) {
            const int k1 = (kt + 1) * 64;
            unsigned short* dK = sK[(kt + 1) & 1];
            unsigned short* dV = sV[(kt + 1) & 1];
#pragma unroll
            for (int c = 0; c < 2; c++) {
                const int chunk = w * 2 + c;
                const int rr = chunk * 8 + crow;
                gl2lds16(&Kh[(size_t)(k1 + rr) * DH + ccs], &dK[chunk * 512]);
                gl2lds16(&Vth[(size_t)rr * SEQ + k1 + ccs], &dV[chunk * 512]);
            }
        }
        const unsigned short* pK = sK[kt & 1];
        const unsigned short* pV = sV[kt & 1];

        bf16x8 kf[8], vf[8];
#pragma unroll
        for (int ks = 0; ks < 2; ks++)
#pragma unroll
            for (int sub = 0; sub < 4; sub++) {
                int rr = sub * 16 + l15;
                int sw = ((ks * 4 + quad) ^ (rr & 7)) * 8;
                kf[ks * 4 + sub] = *(const bf16x8*)&pK[rr * 64 + sw];
                vf[ks * 4 + sub] = *(const bf16x8*)&pV[rr * 64 + sw];
            }

        // ---- S^T = K Q^T (lane holds col=row-of-Q fixed, 16 k-rows)
        f32x4 S4[4];
#pragma unroll
        for (int s = 0; s < 4; s++) S4[s] = (f32x4){0.f, 0.f, 0.f, 0.f};
#pragma unroll
        for (int sub = 0; sub < 4; sub++)
            S4[sub] = __builtin_amdgcn_mfma_f32_16x16x32_bf16(
                kf[sub], q0, S4[sub], 0, 0, 0);
#pragma unroll
        for (int sub = 0; sub < 4; sub++)
            S4[sub] = __builtin_amdgcn_mfma_f32_16x16x32_bf16(
                kf[4 + sub], q1, S4[sub], 0, 0, 0);

        // ---- softmax numerators (Q pre-scaled by log2e/8 -> bare exp2)
        const bool diag = (kt == qt);
#pragma unroll
        for (int sub = 0; sub < 4; sub++) {
            ushort4 o;
            unsigned short* op = (unsigned short*)&o;
#pragma unroll
            for (int r = 0; r < 4; r++) {
                float p = __builtin_exp2f(S4[sub][r]);
                if (diag && (sub * 16 + quad * 4 + r > row)) p = 0.f;
                la += p;
                op[r] = f2bf_fast(p);
            }
            int chunk = sub * 2 + (quad >> 1);
            *(ushort4*)&sP[pwBase + ((chunk ^ (row & 7)) * 8)] = o;
        }
        __builtin_amdgcn_wave_barrier();   // sP rows are wave-private

        // ---- O += V^T P^T
#pragma unroll
        for (int ks = 0; ks < 2; ks++) {
            bf16x8 pb = *(const bf16x8*)
                &sP[prBase + (((ks * 4 + quad) ^ (row & 7)) * 8)];
#pragma unroll
            for (int sub = 0; sub < 4; sub++)
                O[sub] = __builtin_amdgcn_mfma_f32_16x16x32_bf16(
                    vf[ks * 4 + sub], pb, O[sub], 0, 0, 0);
        }
        __builtin_amdgcn_wave_barrier();
    }

    // ---- denominator: sum partials across the 4 quads (same l15)
    la += __shfl_xor(la, 16, 64);
    la += __shfl_xor(la, 32, 64);
    const float rl = 1.0f / la;

    // ---- store: lane owns q = qt*64 + row, e = sub*16 + quad*4 + r
    {
        const int q = qt * 64 + row;
        unsigned short* zrow = Z + ((size_t)b * SEQ + q) * DM + h * DH;
#pragma unroll
        for (int sub = 0; sub < 4; sub++) {
            ushort4 o;
            unsigned short* op = (unsigned short*)&o;
#pragma unroll
            for (int r = 0; r < 4; r++) op[r] = f2bf(O[sub][r] * rl);
            *(ushort4*)&zrow[sub * 16 + quad * 4] = o;
        }
    }
}

// ---------------------------------------------------------------------------
// out_mfma v4: async-prefetch LDS double-buffer, one barrier/iter.
// ---------------------------------------------------------------------------
__global__ __launch_bounds__(256) void out_mfma(
    const unsigned short* __restrict__ Zb,
    const unsigned short* __restrict__ WOt,
    const float* __restrict__ bO,
    float* __restrict__ out)
{
    __shared__ __align__(16) unsigned short sA[2][64 * 64];
    __shared__ __align__(16) unsigned short sB[2][128 * 64];

    const int rowTile = blockIdx.x;
    const int colTile = blockIdx.y;
    const int rowBase = rowTile * 64;
    const int colBase = colTile * 128;

    const int tid  = threadIdx.x;
    const int w    = tid >> 6;
    const int lane = tid & 63;
    const int l15  = lane & 15;
    const int quad = lane >> 4;
    const int rw   = (w & 1) * 32;
    const int cw   = (w >> 1) * 64;

    const int crow = lane >> 3;
    const int ccs  = (((lane & 7) ^ crow) * 8);

    f32x4 acc[2][4];
#pragma unroll
    for (int i = 0; i < 2; i++)
#pragma unroll
        for (int j = 0; j < 4; j++) acc[i][j] = (f32x4){0.f, 0.f, 0.f, 0.f};

    // prologue: stage tile 0
#pragma unroll
    for (int c = 0; c < 2; c++) {
        const int chunk = w * 2 + c;
        const int rr = chunk * 8 + crow;
        gl2lds16(&Zb[(size_t)(rowBase + rr) * DM + ccs], &sA[0][chunk * 512]);
    }
#pragma unroll
    for (int c = 0; c < 4; c++) {
        const int chunk = w * 4 + c;
        const int rr = chunk * 8 + crow;
        gl2lds16(&WOt[(size_t)(colBase + rr) * DM + ccs], &sB[0][chunk * 512]);
    }

    for (int kt = 0; kt < 16; kt++) {
        __syncthreads();
        if (kt < 15) {
            const int k1 = (kt + 1) * 64;
            unsigned short* dA = sA[(kt + 1) & 1];
            unsigned short* dB = sB[(kt + 1) & 1];
#pragma unroll
            for (int c = 0; c < 2; c++) {
                const int chunk = w * 2 + c;
                const int rr = chunk * 8 + crow;
                gl2lds16(&Zb[(size_t)(rowBase + rr) * DM + k1 + ccs], &dA[chunk * 512]);
            }
#pragma unroll
            for (int c = 0; c < 4; c++) {
                const int chunk = w * 4 + c;
                const int rr = chunk * 8 + crow;
                gl2lds16(&WOt[(size_t)(colBase + rr) * DM + k1 + ccs], &dB[chunk * 512]);
            }
        }
        const unsigned short* pA = sA[kt & 1];
        const unsigned short* pB = sB[kt & 1];

#pragma unroll
        for (int ks = 0; ks < 2; ks++) {
            bf16x8 af[2], bf[4];
#pragma unroll
            for (int i = 0; i < 2; i++) {
                int ar = rw + i * 16 + l15;
                af[i] = *(const bf16x8*)&pA[ar * 64 + (((ks * 4 + quad) ^ (ar & 7)) * 8)];
            }
#pragma unroll
            for (int j = 0; j < 4; j++) {
                int br = cw + j * 16 + l15;
                bf[j] = *(const bf16x8*)&pB[br * 64 + (((ks * 4 + quad) ^ (br & 7)) * 8)];
            }
#pragma unroll
            for (int i = 0; i < 2; i++)
#pragma unroll
                for (int j = 0; j < 4; j++)
                    acc[i][j] = __builtin_amdgcn_mfma_f32_16x16x32_bf16(
                        bf[j], af[i], acc[i][j], 0, 0, 0);
        }
    }

#pragma unroll
    for (int i = 0; i < 2; i++) {
        int row = rowBase + rw + i * 16 + l15;
#pragma unroll
        for (int j = 0; j < 4; j++) {
            int col0 = colBase + cw + j * 16 + quad * 4;
            float4 o;
            o.x = acc[i][j][0] + bO[col0 + 0];
            o.y = acc[i][j][1] + bO[col0 + 1];
            o.z = acc[i][j][2] + bO[col0 + 2];
            o.w = acc[i][j][3] + bO[col0 + 3];
            *(float4*)&out[(size_t)row * DM + col0] = o;
        }
    }
}

// ---------------------------------------------------------------------------
extern "C" void kernel_launch(void* const* d_in, const int* in_sizes, int n_in,
                              void* d_out, int out_size, void* d_ws, size_t ws_size,
                              hipStream_t stream)
{
    const float* x  = (const float*)d_in[0];
    const float* WQ = (const float*)d_in[1];
    const float* WK = (const float*)d_in[2];
    const float* WV = (const float*)d_in[3];
    const float* WO = (const float*)d_in[4];
    const float* bQ = (const float*)d_in[5];
    const float* bK = (const float*)d_in[6];
    const float* bV = (const float*)d_in[7];
    const float* bO = (const float*)d_in[8];
    float* out = (float*)d_out;

    const size_t M4 = 4194304;
    unsigned short* xb  = (unsigned short*)d_ws;       // 4M (reused as Zb)
    unsigned short* Wt  = xb + M4;                     // 3M
    unsigned short* WOt = Wt + 3 * 1048576;            // 1M
    unsigned short* Qw  = WOt + 1048576;               // 4M
    unsigned short* Kw  = Qw + M4;                     // 4M
    unsigned short* Vtw = Kw + M4;                     // 4M (transposed V)
    unsigned short* Zb  = xb;

    conv_fused<<<3072, 256, 0, stream>>>(x, WQ, WK, WV, WO, xb, Wt, WOt);

    dim3 g1(32, 24);
    qkv_mfma<<<g1, 256, 0, stream>>>(xb, Wt, bQ, bK, bV, Qw, Kw, Vtw);

    attn_mfma<<<1024, 256, 0, stream>>>(Qw, Kw, Vtw, Zb);

    dim3 g3(64, 8);
    out_mfma<<<g3, 256, 0, stream>>>(Zb, WOt, bO, out);
}

// Round 8
// 185.161 us; speedup vs baseline: 1.0520x; 1.0412x over previous
//
#include <hip/hip_runtime.h>
#include <math.h>

#define BATCH 2
#define SEQ   2048
#define NH    16
#define DH    64
#define DM    1024

typedef __attribute__((ext_vector_type(8))) short bf16x8;
typedef __attribute__((ext_vector_type(8))) unsigned short u16x8;
typedef __attribute__((ext_vector_type(4))) float f32x4;
typedef __attribute__((ext_vector_type(2))) float f32x2;
typedef __attribute__((ext_vector_type(2))) unsigned u32x2;

__device__ __forceinline__ unsigned short f2bf(float f) {
    union { float f; unsigned u; } v; v.f = f;
    unsigned r = v.u + 0x7FFF + ((v.u >> 16) & 1);
    return (unsigned short)(r >> 16);
}
// packed f32 pair -> 2x bf16 in one VALU op (gfx950; T12 primitive)
__device__ __forceinline__ unsigned cvt_pk_bf16(float lo, float hi) {
    unsigned r;
    asm("v_cvt_pk_bf16_f32 %0, %1, %2" : "=v"(r) : "v"(lo), "v"(hi));
    return r;
}

// async global->LDS DMA, 16B per lane; LDS dst = wave-uniform base + lane*16
__device__ __forceinline__ void gl2lds16(const void* g, void* l) {
    __builtin_amdgcn_global_load_lds(
        (const __attribute__((address_space(1))) void*)g,
        (__attribute__((address_space(3))) void*)l,
        16, 0, 0);
}

// 0.125 * log2(e): folded so attn can use raw v_exp_f32 (2^x) directly.
#define QSCALE 0.18033688011112042f

// ---------------------------------------------------------------------------
// conv_fused (round-0): blockIdx < 2048 -> x fp32 -> bf16 ; else weight
// transposes. Standalone x-pass runs at full-chip BW (round-3 lesson: fusing
// it into the occupancy-starved qkv cost +16us).
// ---------------------------------------------------------------------------
__global__ __launch_bounds__(256) void conv_fused(
    const float* __restrict__ x,
    const float* __restrict__ WQ, const float* __restrict__ WK,
    const float* __restrict__ WV, const float* __restrict__ WO,
    unsigned short* __restrict__ xb,
    unsigned short* __restrict__ Wt, unsigned short* __restrict__ WOt)
{
    __shared__ float sT[64][68];
    const int tid = threadIdx.x;

    if (blockIdx.x < 2048) {
        size_t idx = ((size_t)blockIdx.x * 256 + tid) * 8;
        float4 a = *(const float4*)(x + idx);
        float4 b = *(const float4*)(x + idx + 4);
        u16x8 o;
        o[0] = f2bf(a.x); o[1] = f2bf(a.y); o[2] = f2bf(a.z); o[3] = f2bf(a.w);
        o[4] = f2bf(b.x); o[5] = f2bf(b.y); o[6] = f2bf(b.z); o[7] = f2bf(b.w);
        *(u16x8*)(xb + idx) = o;
        return;
    }
    const int t = blockIdx.x - 2048;
    if (t < 768) {
        int m = t >> 8, rem = t & 255, h = rem >> 4, dblk = rem & 15;
        const float* W = (m == 0) ? WQ : (m == 1) ? WK : WV;
        const float* in = W + (size_t)h * 65536 + dblk * 4096;
#pragma unroll
        for (int it = 0; it < 4; it++) {
            int idx = it * 1024 + tid * 4;
            int r = idx >> 6, c = idx & 63;
            *(float4*)(&sT[r][c]) = *(const float4*)(&in[(size_t)r * 64 + c]);
        }
        __syncthreads();
        unsigned short* out = Wt + (size_t)m * 1048576 + (size_t)h * 65536 + dblk * 64;
#pragma unroll
        for (int it = 0; it < 4; it++) {
            int idx = it * 1024 + tid * 4;
            int e = idx >> 6, d0 = idx & 63;
            ushort4 o;
            unsigned short* op = (unsigned short*)&o;
#pragma unroll
            for (int j = 0; j < 4; j++) op[j] = f2bf(sT[d0 + j][e]);
            *(ushort4*)&out[(size_t)e * 1024 + d0] = o;
        }
    } else {
        int tt = t - 768, rblk = tt >> 4, cblk = tt & 15;
        const float* in = WO + (size_t)rblk * 64 * 1024 + cblk * 64;
#pragma unroll
        for (int it = 0; it < 4; it++) {
            int idx = it * 1024 + tid * 4;
            int r = idx >> 6, c = idx & 63;
            *(float4*)(&sT[r][c]) = *(const float4*)(&in[(size_t)r * 1024 + c]);
        }
        __syncthreads();
        unsigned short* out = WOt + (size_t)cblk * 64 * 1024 + rblk * 64;
#pragma unroll
        for (int it = 0; it < 4; it++) {
            int idx = it * 1024 + tid * 4;
            int d = idx >> 6, he0 = idx & 63;
            ushort4 o;
            unsigned short* op = (unsigned short*)&o;
#pragma unroll
            for (int j = 0; j < 4; j++) op[j] = f2bf(sT[he0 + j][d]);
            *(ushort4*)&out[(size_t)d * 1024 + he0] = o;
        }
    }
}

// ---------------------------------------------------------------------------
// qkv_mfma v4 (round-0 structure, best measured 43.9us): async-prefetch LDS
// double-buffer, ONE barrier/iter. 2 blocks/CU (reg-limited 124+64 AGPR;
// round-1 lesson: forcing 3 waves/SIMD spills catastrophically).
// Q output scale folds log2(e) for attn's exp2 path.
// ---------------------------------------------------------------------------
__global__ __launch_bounds__(256) void qkv_mfma(
    const unsigned short* __restrict__ xb,
    const unsigned short* __restrict__ Wt,
    const float* __restrict__ bQ, const float* __restrict__ bK,
    const float* __restrict__ bV,
    unsigned short* __restrict__ Q, unsigned short* __restrict__ K,
    unsigned short* __restrict__ Vt)
{
    __shared__ __align__(16) unsigned short sA[2][128 * 64];
    __shared__ __align__(16) unsigned short sB[2][128 * 64];

    const int rowTile = blockIdx.x;
    const int m  = blockIdx.y >> 3;
    const int hp = blockIdx.y & 7;
    const unsigned short* Wm = Wt + (size_t)m * 1048576 + (size_t)hp * 2 * 65536;

    const int tid  = threadIdx.x;
    const int w    = tid >> 6;
    const int lane = tid & 63;
    const int l15  = lane & 15;
    const int quad = lane >> 4;
    const int rw   = (w & 1) * 64;
    const int cw   = (w >> 1) * 64;
    const int rowBase = rowTile * 128;

    const int crow = lane >> 3;
    const int ccs  = (((lane & 7) ^ crow) * 8);

    f32x4 acc[4][4];
#pragma unroll
    for (int i = 0; i < 4; i++)
#pragma unroll
        for (int j = 0; j < 4; j++) acc[i][j] = (f32x4){0.f, 0.f, 0.f, 0.f};

    // prologue: stage tile 0 into buffer 0
#pragma unroll
    for (int c = 0; c < 4; c++) {
        const int chunk = w * 4 + c;
        const int rr = chunk * 8 + crow;
        gl2lds16(&xb[(size_t)(rowBase + rr) * DM + ccs], &sA[0][chunk * 512]);
        gl2lds16(&Wm[(size_t)rr * DM + ccs],             &sB[0][chunk * 512]);
    }

    for (int kt = 0; kt < 16; kt++) {
        __syncthreads();   // DMA(kt) landed; buf(kt+1&1) free for overwrite
        if (kt < 15) {
            const int k1 = (kt + 1) * 64;
            unsigned short* dA = sA[(kt + 1) & 1];
            unsigned short* dB = sB[(kt + 1) & 1];
#pragma unroll
            for (int c = 0; c < 4; c++) {
                const int chunk = w * 4 + c;
                const int rr = chunk * 8 + crow;
                gl2lds16(&xb[(size_t)(rowBase + rr) * DM + k1 + ccs], &dA[chunk * 512]);
                gl2lds16(&Wm[(size_t)rr * DM + k1 + ccs],             &dB[chunk * 512]);
            }
        }
        const unsigned short* pA = sA[kt & 1];
        const unsigned short* pB = sB[kt & 1];

#pragma unroll
        for (int ks = 0; ks < 2; ks++) {
            bf16x8 af[4], bf[4];
#pragma unroll
            for (int i = 0; i < 4; i++) {
                int ar = rw + i * 16 + l15;
                af[i] = *(const bf16x8*)&pA[ar * 64 + (((ks * 4 + quad) ^ (ar & 7)) * 8)];
            }
#pragma unroll
            for (int j = 0; j < 4; j++) {
                int br = cw + j * 16 + l15;
                bf[j] = *(const bf16x8*)&pB[br * 64 + (((ks * 4 + quad) ^ (br & 7)) * 8)];
            }
            if (m == 2) {
#pragma unroll
                for (int i = 0; i < 4; i++)
#pragma unroll
                    for (int j = 0; j < 4; j++)
                        acc[i][j] = __builtin_amdgcn_mfma_f32_16x16x32_bf16(
                            af[i], bf[j], acc[i][j], 0, 0, 0);
            } else {
#pragma unroll
                for (int i = 0; i < 4; i++)
#pragma unroll
                    for (int j = 0; j < 4; j++)
                        acc[i][j] = __builtin_amdgcn_mfma_f32_16x16x32_bf16(
                            bf[j], af[i], acc[i][j], 0, 0, 0);
            }
        }
    }

    if (m == 2) {
        // D[m=s][n=e]: lane holds fixed e, 4 consecutive s -> Vt[e][s] packed
#pragma unroll
        for (int j = 0; j < 4; j++) {
            int col = cw + j * 16 + l15;
            int h = hp * 2 + (col >> 6);
            int e = col & 63;
            float bv = bV[h * DH + e];
#pragma unroll
            for (int i = 0; i < 4; i++) {
                int row0 = rowBase + rw + i * 16 + quad * 4;
                int b = row0 >> 11, s0 = row0 & 2047;
                ushort4 o;
                unsigned short* op = (unsigned short*)&o;
#pragma unroll
                for (int r = 0; r < 4; r++) op[r] = f2bf(acc[i][j][r] + bv);
                *(ushort4*)&Vt[(((size_t)b * NH + h) * DH + e) * SEQ + s0] = o;
            }
        }
    } else {
        // D[m=e][n=s]: lane holds fixed s, 4 consecutive e -> [s][e] packed
        const float* bias = (m == 0) ? bQ : bK;
        unsigned short* Out = (m == 0) ? Q : K;
        const float scale = (m == 0) ? QSCALE : 1.0f;
        float4 bb[4];
        int hj[4], e0j[4];
#pragma unroll
        for (int j = 0; j < 4; j++) {
            int col0 = cw + j * 16 + quad * 4;
            hj[j] = hp * 2 + (col0 >> 6);
            e0j[j] = col0 & 63;
            bb[j] = *(const float4*)&bias[hj[j] * DH + e0j[j]];
        }
#pragma unroll
        for (int i = 0; i < 4; i++) {
            int row = rowBase + rw + i * 16 + l15;
            int b = row >> 11, s = row & 2047;
#pragma unroll
            for (int j = 0; j < 4; j++) {
                const float* bp = (const float*)&bb[j];
                ushort4 o;
                unsigned short* op = (unsigned short*)&o;
#pragma unroll
                for (int r = 0; r < 4; r++)
                    op[r] = f2bf((acc[i][j][r] + bp[r]) * scale);
                *(ushort4*)&Out[(((size_t)b * NH + hj[j]) * SEQ + s) * DH + e0j[j]] = o;
            }
        }
    }
}

// ---------------------------------------------------------------------------
// attn_mfma v12: v9 dispatch order (qt = 31 - t, longest-first) + VALU diet.
// DISPATCH LESSON (rounds 5-7, final): blocks are DYNAMICALLY scheduled into
// slots as they free (occupancy ~24% => <4 blocks/CU resident despite LDS
// fitting 4). Descending-qt order IS the LPT greedy schedule and measured
// fastest (44.2us); both "balanced" static remaps broke LPT and regressed
// to 50.4us. Do not model the dispatcher; dispatch longest work first.
// VALU DIET (counters: VALUBusy 53%, MfmaUtil 13.6% -> VALU-bound):
//  - v_cvt_pk_bf16_f32 packs P pairs (1 op / 2 elems, replaces bit-trick
//    f2bf + manual packing).
//  - f32x2 packed la accumulators (v_pk_add_f32): 16 serial adds -> 8 packed
//    in 2 chains.
//  - diag mask hoisted into a wave-uniform branch: 31/32 iterations emit no
//    cmp/cndmask.
// ---------------------------------------------------------------------------
__global__ __launch_bounds__(256) void attn_mfma(
    const unsigned short* __restrict__ Q,    // [B][H][S][E] bf16, pre-scaled
    const unsigned short* __restrict__ K,    // [B][H][S][E] bf16
    const unsigned short* __restrict__ Vt,   // [B][H][E][S] bf16
    unsigned short* __restrict__ Z)          // [B][S][H*E] bf16
{
    __shared__ __align__(16) unsigned short sK[2][64 * 64];
    __shared__ __align__(16) unsigned short sV[2][64 * 64];
    __shared__ __align__(16) unsigned short sP[64 * 64];

    const int h  = blockIdx.x & 15;
    const int b  = (blockIdx.x >> 4) & 1;
    const int qt = 31 - (blockIdx.x >> 5);    // LPT: long tiles first

    const int tid  = threadIdx.x;
    const int w    = tid >> 6;
    const int lane = tid & 63;
    const int l15  = lane & 15;
    const int quad = lane >> 4;
    const int row  = w * 16 + l15;            // q-row within the 64-row tile

    const size_t headOff = ((size_t)b * NH + h) * SEQ * DH;
    const unsigned short* Qh  = Q  + headOff;
    const unsigned short* Kh  = K  + headOff;
    const unsigned short* Vth = Vt + headOff;   // [E][S]

    const unsigned short* qrow =
        Qh + (size_t)(qt * 64 + row) * DH + quad * 8;
    bf16x8 q0 = *(const bf16x8*)(qrow);
    bf16x8 q1 = *(const bf16x8*)(qrow + 32);

    f32x4 O[4];
#pragma unroll
    for (int s = 0; s < 4; s++) O[s] = (f32x4){0.f, 0.f, 0.f, 0.f};
    f32x2 la2a = (f32x2){0.f, 0.f};
    f32x2 la2b = (f32x2){0.f, 0.f};

    const int crow = lane >> 3;
    const int ccs  = (((lane & 7) ^ crow) * 8);

    // prologue: stage tile 0 into buffer 0
#pragma unroll
    for (int c = 0; c < 2; c++) {
        const int chunk = w * 2 + c;
        const int rr = chunk * 8 + crow;
        gl2lds16(&Kh[(size_t)rr * DH + ccs],   &sK[0][chunk * 512]);
        gl2lds16(&Vth[(size_t)rr * SEQ + ccs], &sV[0][chunk * 512]);
    }

    // P LDS addressing: element (row, col) lives at
    //   row*64 + ((col>>3) ^ (row&7))*8 + (col&7)
    const int pwBase = row * 64 + (quad & 1) * 4;   // + chunk-swizzle per sub
    const int prBase = row * 64;

    for (int kt = 0; kt <= qt; kt++) {
        __syncthreads();   // DMA(kt) landed; other buffer free
        if (kt < qt) {
            const int k1 = (kt + 1) * 64;
            unsigned short* dK = sK[(kt + 1) & 1];
            unsigned short* dV = sV[(kt + 1) & 1];
#pragma unroll
            for (int c = 0; c < 2; c++) {
                const int chunk = w * 2 + c;
                const int rr = chunk * 8 + crow;
                gl2lds16(&Kh[(size_t)(k1 + rr) * DH + ccs], &dK[chunk * 512]);
                gl2lds16(&Vth[(size_t)rr * SEQ + k1 + ccs], &dV[chunk * 512]);
            }
        }
        const unsigned short* pK = sK[kt & 1];
        const unsigned short* pV = sV[kt & 1];

        bf16x8 kf[8], vf[8];
#pragma unroll
        for (int ks = 0; ks < 2; ks++)
#pragma unroll
            for (int sub = 0; sub < 4; sub++) {
                int rr = sub * 16 + l15;
                int sw = ((ks * 4 + quad) ^ (rr & 7)) * 8;
                kf[ks * 4 + sub] = *(const bf16x8*)&pK[rr * 64 + sw];
                vf[ks * 4 + sub] = *(const bf16x8*)&pV[rr * 64 + sw];
            }

        // ---- S^T = K Q^T (lane holds col=row-of-Q fixed, 16 k-rows)
        f32x4 S4[4];
#pragma unroll
        for (int s = 0; s < 4; s++) S4[s] = (f32x4){0.f, 0.f, 0.f, 0.f};
#pragma unroll
        for (int sub = 0; sub < 4; sub++)
            S4[sub] = __builtin_amdgcn_mfma_f32_16x16x32_bf16(
                kf[sub], q0, S4[sub], 0, 0, 0);
#pragma unroll
        for (int sub = 0; sub < 4; sub++)
            S4[sub] = __builtin_amdgcn_mfma_f32_16x16x32_bf16(
                kf[4 + sub], q1, S4[sub], 0, 0, 0);

        // ---- softmax numerators (Q pre-scaled by log2e/8 -> bare exp2)
        // VALU diet: exp2 -> (diag-only mask) -> pk_add la -> cvt_pk pack.
        if (kt == qt) {
#pragma unroll
            for (int sub = 0; sub < 4; sub++) {
                float p[4];
#pragma unroll
                for (int r = 0; r < 4; r++) {
                    p[r] = __builtin_exp2f(S4[sub][r]);
                    if (sub * 16 + quad * 4 + r > row) p[r] = 0.f;
                }
                la2a += (f32x2){p[0], p[1]};
                la2b += (f32x2){p[2], p[3]};
                u32x2 pk;
                pk.x = cvt_pk_bf16(p[0], p[1]);
                pk.y = cvt_pk_bf16(p[2], p[3]);
                int chunk = sub * 2 + (quad >> 1);
                *(u32x2*)&sP[pwBase + ((chunk ^ (row & 7)) * 8)] = pk;
            }
        } else {
#pragma unroll
            for (int sub = 0; sub < 4; sub++) {
                float p[4];
#pragma unroll
                for (int r = 0; r < 4; r++) p[r] = __builtin_exp2f(S4[sub][r]);
                la2a += (f32x2){p[0], p[1]};
                la2b += (f32x2){p[2], p[3]};
                u32x2 pk;
                pk.x = cvt_pk_bf16(p[0], p[1]);
                pk.y = cvt_pk_bf16(p[2], p[3]);
                int chunk = sub * 2 + (quad >> 1);
                *(u32x2*)&sP[pwBase + ((chunk ^ (row & 7)) * 8)] = pk;
            }
        }
        __builtin_amdgcn_wave_barrier();   // sP rows are wave-private

        // ---- O += V^T P^T
#pragma unroll
        for (int ks = 0; ks < 2; ks++) {
            bf16x8 pb = *(const bf16x8*)
                &sP[prBase + (((ks * 4 + quad) ^ (row & 7)) * 8)];
#pragma unroll
            for (int sub = 0; sub < 4; sub++)
                O[sub] = __builtin_amdgcn_mfma_f32_16x16x32_bf16(
                    vf[ks * 4 + sub], pb, O[sub], 0, 0, 0);
        }
        __builtin_amdgcn_wave_barrier();
    }

    // ---- denominator: sum partials across the 4 quads (same l15)
    float la = la2a.x + la2a.y + la2b.x + la2b.y;
    la += __shfl_xor(la, 16, 64);
    la += __shfl_xor(la, 32, 64);
    const float rl = 1.0f / la;

    // ---- store: lane owns q = qt*64 + row, e = sub*16 + quad*4 + r
    {
        const int q = qt * 64 + row;
        unsigned short* zrow = Z + ((size_t)b * SEQ + q) * DM + h * DH;
#pragma unroll
        for (int sub = 0; sub < 4; sub++) {
            ushort4 o;
            unsigned short* op = (unsigned short*)&o;
#pragma unroll
            for (int r = 0; r < 4; r++) op[r] = f2bf(O[sub][r] * rl);
            *(ushort4*)&zrow[sub * 16 + quad * 4] = o;
        }
    }
}

// ---------------------------------------------------------------------------
// out_mfma v4: async-prefetch LDS double-buffer, one barrier/iter.
// ---------------------------------------------------------------------------
__global__ __launch_bounds__(256) void out_mfma(
    const unsigned short* __restrict__ Zb,
    const unsigned short* __restrict__ WOt,
    const float* __restrict__ bO,
    float* __restrict__ out)
{
    __shared__ __align__(16) unsigned short sA[2][64 * 64];
    __shared__ __align__(16) unsigned short sB[2][128 * 64];

    const int rowTile = blockIdx.x;
    const int colTile = blockIdx.y;
    const int rowBase = rowTile * 64;
    const int colBase = colTile * 128;

    const int tid  = threadIdx.x;
    const int w    = tid >> 6;
    const int lane = tid & 63;
    const int l15  = lane & 15;
    const int quad = lane >> 4;
    const int rw   = (w & 1) * 32;
    const int cw   = (w >> 1) * 64;

    const int crow = lane >> 3;
    const int ccs  = (((lane & 7) ^ crow) * 8);

    f32x4 acc[2][4];
#pragma unroll
    for (int i = 0; i < 2; i++)
#pragma unroll
        for (int j = 0; j < 4; j++) acc[i][j] = (f32x4){0.f, 0.f, 0.f, 0.f};

    // prologue: stage tile 0
#pragma unroll
    for (int c = 0; c < 2; c++) {
        const int chunk = w * 2 + c;
        const int rr = chunk * 8 + crow;
        gl2lds16(&Zb[(size_t)(rowBase + rr) * DM + ccs], &sA[0][chunk * 512]);
    }
#pragma unroll
    for (int c = 0; c < 4; c++) {
        const int chunk = w * 4 + c;
        const int rr = chunk * 8 + crow;
        gl2lds16(&WOt[(size_t)(colBase + rr) * DM + ccs], &sB[0][chunk * 512]);
    }

    for (int kt = 0; kt < 16; kt++) {
        __syncthreads();
        if (kt < 15) {
            const int k1 = (kt + 1) * 64;
            unsigned short* dA = sA[(kt + 1) & 1];
            unsigned short* dB = sB[(kt + 1) & 1];
#pragma unroll
            for (int c = 0; c < 2; c++) {
                const int chunk = w * 2 + c;
                const int rr = chunk * 8 + crow;
                gl2lds16(&Zb[(size_t)(rowBase + rr) * DM + k1 + ccs], &dA[chunk * 512]);
            }
#pragma unroll
            for (int c = 0; c < 4; c++) {
                const int chunk = w * 4 + c;
                const int rr = chunk * 8 + crow;
                gl2lds16(&WOt[(size_t)(colBase + rr) * DM + k1 + ccs], &dB[chunk * 512]);
            }
        }
        const unsigned short* pA = sA[kt & 1];
        const unsigned short* pB = sB[kt & 1];

#pragma unroll
        for (int ks = 0; ks < 2; ks++) {
            bf16x8 af[2], bf[4];
#pragma unroll
            for (int i = 0; i < 2; i++) {
                int ar = rw + i * 16 + l15;
                af[i] = *(const bf16x8*)&pA[ar * 64 + (((ks * 4 + quad) ^ (ar & 7)) * 8)];
            }
#pragma unroll
            for (int j = 0; j < 4; j++) {
                int br = cw + j * 16 + l15;
                bf[j] = *(const bf16x8*)&pB[br * 64 + (((ks * 4 + quad) ^ (br & 7)) * 8)];
            }
#pragma unroll
            for (int i = 0; i < 2; i++)
#pragma unroll
                for (int j = 0; j < 4; j++)
                    acc[i][j] = __builtin_amdgcn_mfma_f32_16x16x32_bf16(
                        bf[j], af[i], acc[i][j], 0, 0, 0);
        }
    }

#pragma unroll
    for (int i = 0; i < 2; i++) {
        int row = rowBase + rw + i * 16 + l15;
#pragma unroll
        for (int j = 0; j < 4; j++) {
            int col0 = colBase + cw + j * 16 + quad * 4;
            float4 o;
            o.x = acc[i][j][0] + bO[col0 + 0];
            o.y = acc[i][j][1] + bO[col0 + 1];
            o.z = acc[i][j][2] + bO[col0 + 2];
            o.w = acc[i][j][3] + bO[col0 + 3];
            *(float4*)&out[(size_t)row * DM + col0] = o;
        }
    }
}

// ---------------------------------------------------------------------------
extern "C" void kernel_launch(void* const* d_in, const int* in_sizes, int n_in,
                              void* d_out, int out_size, void* d_ws, size_t ws_size,
                              hipStream_t stream)
{
    const float* x  = (const float*)d_in[0];
    const float* WQ = (const float*)d_in[1];
    const float* WK = (const float*)d_in[2];
    const float* WV = (const float*)d_in[3];
    const float* WO = (const float*)d_in[4];
    const float* bQ = (const float*)d_in[5];
    const float* bK = (const float*)d_in[6];
    const float* bV = (const float*)d_in[7];
    const float* bO = (const float*)d_in[8];
    float* out = (float*)d_out;

    const size_t M4 = 4194304;
    unsigned short* xb  = (unsigned short*)d_ws;       // 4M (reused as Zb)
    unsigned short* Wt  = xb + M4;                     // 3M
    unsigned short* WOt = Wt + 3 * 1048576;            // 1M
    unsigned short* Qw  = WOt + 1048576;               // 4M
    unsigned short* Kw  = Qw + M4;                     // 4M
    unsigned short* Vtw = Kw + M4;                     // 4M (transposed V)
    unsigned short* Zb  = xb;

    conv_fused<<<3072, 256, 0, stream>>>(x, WQ, WK, WV, WO, xb, Wt, WOt);

    dim3 g1(32, 24);
    qkv_mfma<<<g1, 256, 0, stream>>>(xb, Wt, bQ, bK, bV, Qw, Kw, Vtw);

    attn_mfma<<<1024, 256, 0, stream>>>(Qw, Kw, Vtw, Zb);

    dim3 g3(64, 8);
    out_mfma<<<g3, 256, 0, stream>>>(Zb, WOt, bO, out);
}